// Round 5
// baseline (50.965 us; speedup 1.0000x reference)
//
#include <hip/hip_runtime.h>

#define TPB 256
// Sample bases are 36B-aligned -> 16B loads at align-4 (HW-supported on gfx9+).
typedef float v4fa __attribute__((ext_vector_type(4), aligned(4)));

#define NTS(v, p)  __builtin_nontemporal_store((v), (p))

// One Euler-Maruyama step with closed-form polar (Rodrigues) retraction.
// x <- x * (I + c1*S + c2*S^2), S = hs*(x^T e - e^T x) skew, axial (A,Bv,Cv).
__device__ __forceinline__ void so3_step(float x[9], const float e[9], float hs) {
    float wa = 0.f, wb = 0.f, wc = 0.f;
    #pragma unroll
    for (int k = 0; k < 3; ++k) {
        const float xk0 = x[k*3+0], xk1 = x[k*3+1], xk2 = x[k*3+2];
        const float ek0 = e[k*3+0], ek1 = e[k*3+1], ek2 = e[k*3+2];
        wa += xk2*ek1 - xk1*ek2;
        wb += xk0*ek2 - xk2*ek0;
        wc += xk1*ek0 - xk0*ek1;
    }
    const float A  = hs * wa;
    const float Bv = hs * wb;
    const float Cv = hs * wc;

    const float th2 = A*A + Bv*Bv + Cv*Cv;
    const float c1  = rsqrtf(1.0f + th2);
    const float c2  = c1*c1 / (1.0f + c1);   // (1 - c1)/th2, stable at th2 -> 0

    const float q00 = 1.0f - c2*(Bv*Bv + Cv*Cv);
    const float q11 = 1.0f - c2*(A*A  + Cv*Cv);
    const float q22 = 1.0f - c2*(A*A  + Bv*Bv);
    const float q01 = c2*A*Bv  - c1*Cv;
    const float q10 = c2*A*Bv  + c1*Cv;
    const float q02 = c2*A*Cv  + c1*Bv;
    const float q20 = c2*A*Cv  - c1*Bv;
    const float q12 = c2*Bv*Cv - c1*A;
    const float q21 = c2*Bv*Cv + c1*A;

    #pragma unroll
    for (int r = 0; r < 3; ++r) {
        const float a0 = x[r*3+0], a1 = x[r*3+1], a2 = x[r*3+2];
        x[r*3+0] = a0*q00 + a1*q10 + a2*q20;
        x[r*3+1] = a0*q01 + a1*q11 + a2*q21;
        x[r*3+2] = a0*q02 + a1*q12 + a2*q22;
    }
}

__device__ __forceinline__ void load9(const float* __restrict__ p, float e[9]) {
    v4fa lo = *(const v4fa*)(p);
    v4fa hi = *(const v4fa*)(p + 4);
    e[0] = lo.x; e[1] = lo.y; e[2] = lo.z; e[3] = lo.w;
    e[4] = hi.x; e[5] = hi.y; e[6] = hi.z; e[7] = hi.w;
    e[8] = p[8];
}

__device__ __forceinline__ void load9nt(const float* __restrict__ p, float e[9]) {
    v4fa lo = __builtin_nontemporal_load((const v4fa*)(p));
    v4fa hi = __builtin_nontemporal_load((const v4fa*)(p + 4));
    float w = __builtin_nontemporal_load(p + 8);
    e[0] = lo.x; e[1] = lo.y; e[2] = lo.z; e[3] = lo.w;
    e[4] = hi.x; e[5] = hi.y; e[6] = hi.z; e[7] = hi.w;
    e[8] = w;
}

__global__ __launch_bounds__(TPB) void brownian_so3_kernel(
    const float* __restrict__ x0,
    const float* __restrict__ t,
    const float* __restrict__ noise,
    float* __restrict__ out,
    int B, int steps)
{
    const int b = blockIdx.x * TPB + threadIdx.x;   // one sample per thread

    const float tv = t[b];

    float x[9];
    load9(x0 + (long)b * 9, x);

    const long stride = (long)B * 9;
    const float* np = noise + (long)b * 9;

    // A/B register sets: A = even tiles, B = odd tiles.
    float A[9], Bb[9];
    load9nt(np, A);
    if (steps > 1) load9nt(np + stride, Bb);

    const float hs = 0.5f * sqrtf(tv / (float)steps);

    int s = 0;
    // Main unroll-2 loop: issue loads for s+2/s+3 FIRST, compute steps s and
    // s+1, THEN retire LA->A / LB->B. The vmcnt wait for a tile lands two
    // full steps after its issue -> true depth-2 flight.
    for (; s + 3 < steps; s += 2) {
        float LA[9], LB[9];
        load9nt(np + (long)(s + 2) * stride, LA);
        load9nt(np + (long)(s + 3) * stride, LB);
        so3_step(x, A,  hs);
        so3_step(x, Bb, hs);
        #pragma unroll
        for (int j = 0; j < 9; ++j) { A[j] = LA[j]; Bb[j] = LB[j]; }
    }
    // Tail: 1..3 tiles remain (3 only when steps is odd).
    if (steps - s == 3) {
        float LC[9];
        load9nt(np + (long)(s + 2) * stride, LC);
        so3_step(x, A,  hs);
        so3_step(x, Bb, hs);
        so3_step(x, LC, hs);
    } else if (steps - s == 2) {
        so3_step(x, A,  hs);
        so3_step(x, Bb, hs);
    } else if (steps - s == 1) {
        so3_step(x, A,  hs);
    }

    // Direct per-lane NT store of the 9 result floats.
    float* op = out + (long)b * 9;
    v4fa lo, hi;
    lo.x = x[0]; lo.y = x[1]; lo.z = x[2]; lo.w = x[3];
    hi.x = x[4]; hi.y = x[5]; hi.z = x[6]; hi.w = x[7];
    NTS(lo, (v4fa*)op);
    NTS(hi, (v4fa*)(op + 4));
    NTS(x[8], op + 8);
}

extern "C" void kernel_launch(void* const* d_in, const int* in_sizes, int n_in,
                              void* d_out, int out_size, void* d_ws, size_t ws_size,
                              hipStream_t stream) {
    const float* x0    = (const float*)d_in[0];
    const float* t     = (const float*)d_in[1];
    const float* noise = (const float*)d_in[2];
    float* out = (float*)d_out;

    const int B     = in_sizes[0] / 9;
    const int steps = in_sizes[2] / in_sizes[0];

    const int grid = B / TPB;   // 262144 / 256 = 1024 blocks
    brownian_so3_kernel<<<grid, TPB, 0, stream>>>(x0, t, noise, out, B, steps);
}

// Round 6
// 37.931 us; speedup vs baseline: 1.3436x; 1.3436x over previous
//
#include <hip/hip_runtime.h>

#define TPB 256
// Sample bases are 36B-aligned -> 16B loads at align-4 (HW-supported on gfx9+).
typedef float v4fa __attribute__((ext_vector_type(4), aligned(4)));

#define NTS(v, p)  __builtin_nontemporal_store((v), (p))

// One Euler-Maruyama step with closed-form polar (Rodrigues) retraction.
// x <- x * (I + c1*S + c2*S^2), S = hs*(x^T e - e^T x) skew, axial (A,Bv,Cv).
__device__ __forceinline__ void so3_step(float x[9], const float e[9], float hs) {
    float wa = 0.f, wb = 0.f, wc = 0.f;
    #pragma unroll
    for (int k = 0; k < 3; ++k) {
        const float xk0 = x[k*3+0], xk1 = x[k*3+1], xk2 = x[k*3+2];
        const float ek0 = e[k*3+0], ek1 = e[k*3+1], ek2 = e[k*3+2];
        wa += xk2*ek1 - xk1*ek2;
        wb += xk0*ek2 - xk2*ek0;
        wc += xk1*ek0 - xk0*ek1;
    }
    const float A  = hs * wa;
    const float Bv = hs * wb;
    const float Cv = hs * wc;

    const float th2 = A*A + Bv*Bv + Cv*Cv;
    const float c1  = rsqrtf(1.0f + th2);
    const float c2  = c1*c1 / (1.0f + c1);   // (1 - c1)/th2, stable at th2 -> 0

    const float q00 = 1.0f - c2*(Bv*Bv + Cv*Cv);
    const float q11 = 1.0f - c2*(A*A  + Cv*Cv);
    const float q22 = 1.0f - c2*(A*A  + Bv*Bv);
    const float q01 = c2*A*Bv  - c1*Cv;
    const float q10 = c2*A*Bv  + c1*Cv;
    const float q02 = c2*A*Cv  + c1*Bv;
    const float q20 = c2*A*Cv  - c1*Bv;
    const float q12 = c2*Bv*Cv - c1*A;
    const float q21 = c2*Bv*Cv + c1*A;

    #pragma unroll
    for (int r = 0; r < 3; ++r) {
        const float a0 = x[r*3+0], a1 = x[r*3+1], a2 = x[r*3+2];
        x[r*3+0] = a0*q00 + a1*q10 + a2*q20;
        x[r*3+1] = a0*q01 + a1*q11 + a2*q21;
        x[r*3+2] = a0*q02 + a1*q12 + a2*q22;
    }
}

// Plain (cached) loads — NT on this overlapping 36B-granular pattern causes
// HBM refetch of straddled lines (R5 post-mortem: 37.7 -> 51 us).
__device__ __forceinline__ void load9(const float* __restrict__ p, float e[9]) {
    v4fa lo = *(const v4fa*)(p);
    v4fa hi = *(const v4fa*)(p + 4);
    e[0] = lo.x; e[1] = lo.y; e[2] = lo.z; e[3] = lo.w;
    e[4] = hi.x; e[5] = hi.y; e[6] = hi.z; e[7] = hi.w;
    e[8] = p[8];
}

__global__ __launch_bounds__(TPB) void brownian_so3_kernel(
    const float* __restrict__ x0,
    const float* __restrict__ t,
    const float* __restrict__ noise,
    float* __restrict__ out,
    int B, int steps)
{
    const int b = blockIdx.x * TPB + threadIdx.x;   // one sample per thread

    const float tv = t[b];

    float x[9];
    load9(x0 + (long)b * 9, x);

    const long stride = (long)B * 9;
    const float* np = noise + (long)b * 9;

    // A/B register buffers: A = even tiles, B = odd tiles.
    float A[9], Bb[9];
    load9(np, A);
    if (steps > 1) load9(np + stride, Bb);

    const float hs = 0.5f * sqrtf(tv / (float)steps);

    int s = 0;
    // Unroll-2 rotation: each buffer is refilled IMMEDIATELY AFTER its
    // consuming step and next consumed two steps later -> every load has
    // ~2 step-times (>HBM latency) of flight. No renaming copies, no LDS,
    // no barriers.
    for (; s + 3 < steps; s += 2) {
        so3_step(x, A,  hs);                        // consume tile s
        load9(np + (long)(s + 2) * stride, A);      // refill A with tile s+2
        so3_step(x, Bb, hs);                        // consume tile s+1
        load9(np + (long)(s + 3) * stride, Bb);     // refill B with tile s+3
    }
    // Tail: 2 tiles remain when steps is even (steps=20 -> s=18 here),
    // 3 when odd.
    if (steps - s == 3) {
        so3_step(x, A,  hs);
        load9(np + (long)(s + 2) * stride, A);
        so3_step(x, Bb, hs);
        so3_step(x, A,  hs);
    } else if (steps - s == 2) {
        so3_step(x, A,  hs);
        so3_step(x, Bb, hs);
    } else if (steps - s == 1) {
        so3_step(x, A,  hs);
    }

    // Direct per-lane NT store (write-once stream; disjoint lines per instr
    // are safe for NT, and out is never re-read).
    float* op = out + (long)b * 9;
    v4fa lo, hi;
    lo.x = x[0]; lo.y = x[1]; lo.z = x[2]; lo.w = x[3];
    hi.x = x[4]; hi.y = x[5]; hi.z = x[6]; hi.w = x[7];
    NTS(lo, (v4fa*)op);
    NTS(hi, (v4fa*)(op + 4));
    NTS(x[8], op + 8);
}

extern "C" void kernel_launch(void* const* d_in, const int* in_sizes, int n_in,
                              void* d_out, int out_size, void* d_ws, size_t ws_size,
                              hipStream_t stream) {
    const float* x0    = (const float*)d_in[0];
    const float* t     = (const float*)d_in[1];
    const float* noise = (const float*)d_in[2];
    float* out = (float*)d_out;

    const int B     = in_sizes[0] / 9;
    const int steps = in_sizes[2] / in_sizes[0];

    const int grid = B / TPB;   // 262144 / 256 = 1024 blocks
    brownian_so3_kernel<<<grid, TPB, 0, stream>>>(x0, t, noise, out, B, steps);
}

// Round 7
// 37.809 us; speedup vs baseline: 1.3480x; 1.0032x over previous
//
#include <hip/hip_runtime.h>

#define TPB 256
// Sample bases are 36B-aligned -> 16B loads at align-4 (HW-supported on gfx9+).
typedef float v4fa __attribute__((ext_vector_type(4), aligned(4)));

// One Euler-Maruyama step with closed-form polar (Rodrigues) retraction.
// x <- x * (I + c1*S + c2*S^2), S = hs*(x^T e - e^T x) skew, axial (A,Bv,Cv).
__device__ __forceinline__ void so3_step(float x[9], const float e[9], float hs) {
    float wa = 0.f, wb = 0.f, wc = 0.f;
    #pragma unroll
    for (int k = 0; k < 3; ++k) {
        const float xk0 = x[k*3+0], xk1 = x[k*3+1], xk2 = x[k*3+2];
        const float ek0 = e[k*3+0], ek1 = e[k*3+1], ek2 = e[k*3+2];
        wa += xk2*ek1 - xk1*ek2;
        wb += xk0*ek2 - xk2*ek0;
        wc += xk1*ek0 - xk0*ek1;
    }
    const float A  = hs * wa;
    const float Bv = hs * wb;
    const float Cv = hs * wc;

    const float th2 = A*A + Bv*Bv + Cv*Cv;
    const float c1  = rsqrtf(1.0f + th2);
    const float c2  = c1*c1 / (1.0f + c1);   // (1 - c1)/th2, stable at th2 -> 0

    const float q00 = 1.0f - c2*(Bv*Bv + Cv*Cv);
    const float q11 = 1.0f - c2*(A*A  + Cv*Cv);
    const float q22 = 1.0f - c2*(A*A  + Bv*Bv);
    const float q01 = c2*A*Bv  - c1*Cv;
    const float q10 = c2*A*Bv  + c1*Cv;
    const float q02 = c2*A*Cv  + c1*Bv;
    const float q20 = c2*A*Cv  - c1*Bv;
    const float q12 = c2*Bv*Cv - c1*A;
    const float q21 = c2*Bv*Cv + c1*A;

    #pragma unroll
    for (int r = 0; r < 3; ++r) {
        const float a0 = x[r*3+0], a1 = x[r*3+1], a2 = x[r*3+2];
        x[r*3+0] = a0*q00 + a1*q10 + a2*q20;
        x[r*3+1] = a0*q01 + a1*q11 + a2*q21;
        x[r*3+2] = a0*q02 + a1*q12 + a2*q22;
    }
}

// Plain (cached) loads — NT on this overlapping 36B-granular pattern causes
// HBM refetch of straddled lines (R5 post-mortem: 37.7 -> 51 us).
__device__ __forceinline__ void load9(const float* __restrict__ p, float e[9]) {
    v4fa lo = *(const v4fa*)(p);
    v4fa hi = *(const v4fa*)(p + 4);
    e[0] = lo.x; e[1] = lo.y; e[2] = lo.z; e[3] = lo.w;
    e[4] = hi.x; e[5] = hi.y; e[6] = hi.z; e[7] = hi.w;
    e[8] = p[8];
}

__global__ __launch_bounds__(TPB) void brownian_so3_kernel(
    const float* __restrict__ x0,
    const float* __restrict__ t,
    const float* __restrict__ noise,
    float* __restrict__ out,
    int B, int steps)
{
    const int b = blockIdx.x * TPB + threadIdx.x;   // one sample per thread

    const float tv = t[b];

    float x[9];
    load9(x0 + (long)b * 9, x);

    const long stride = (long)B * 9;
    const float* np = noise + (long)b * 9;

    // A/B register buffers: A = even tiles, B = odd tiles.
    float A[9], Bb[9];
    load9(np, A);
    if (steps > 1) load9(np + stride, Bb);

    const float hs = 0.5f * sqrtf(tv / (float)steps);

    int s = 0;
    // Unroll-2 rotation: each buffer is refilled immediately after its
    // consuming step and next consumed two steps later -> ~2 step-times of
    // load flight. No LDS, no barriers.
    for (; s + 3 < steps; s += 2) {
        so3_step(x, A,  hs);                        // consume tile s
        load9(np + (long)(s + 2) * stride, A);      // refill A with tile s+2
        so3_step(x, Bb, hs);                        // consume tile s+1
        load9(np + (long)(s + 3) * stride, Bb);     // refill B with tile s+3
    }
    if (steps - s == 3) {
        so3_step(x, A,  hs);
        load9(np + (long)(s + 2) * stride, A);
        so3_step(x, Bb, hs);
        so3_step(x, A,  hs);
    } else if (steps - s == 2) {
        so3_step(x, A,  hs);
        so3_step(x, Bb, hs);
    } else if (steps - s == 1) {
        so3_step(x, A,  hs);
    }

    // PLAIN stores (the one change vs R6): let the caches assemble full 64B
    // lines from the waves' contiguous 2304B store range, avoiding partial-
    // line ECC read-modify-write that the NT hint may force.
    float* op = out + (long)b * 9;
    v4fa lo, hi;
    lo.x = x[0]; lo.y = x[1]; lo.z = x[2]; lo.w = x[3];
    hi.x = x[4]; hi.y = x[5]; hi.z = x[6]; hi.w = x[7];
    *(v4fa*)op       = lo;
    *(v4fa*)(op + 4) = hi;
    op[8] = x[8];
}

extern "C" void kernel_launch(void* const* d_in, const int* in_sizes, int n_in,
                              void* d_out, int out_size, void* d_ws, size_t ws_size,
                              hipStream_t stream) {
    const float* x0    = (const float*)d_in[0];
    const float* t     = (const float*)d_in[1];
    const float* noise = (const float*)d_in[2];
    float* out = (float*)d_out;

    const int B     = in_sizes[0] / 9;
    const int steps = in_sizes[2] / in_sizes[0];

    const int grid = B / TPB;   // 262144 / 256 = 1024 blocks
    brownian_so3_kernel<<<grid, TPB, 0, stream>>>(x0, t, noise, out, B, steps);
}